// Round 1
// 538.337 us; speedup vs baseline: 1.0138x; 1.0138x over previous
//
#include <hip/hip_runtime.h>
#include <hip/hip_bf16.h>
#include <cmath>

// ---------------------------------------------------------------------------
// GAT 2-layer forward.
//  - LDS-free MFMA GEMMs (A direct global->reg, B pre-transposed bf16).
//  - scores1 fused into GEMM1 (extra 16 output cols via Wa = W1 @ blockdiag(a)).
//  - h1 stored BIASED UINT8 (q+128) with per-row scale -> agg1 unpacks with
//    v_cvt_f32_ubyte{0..3} (1 op/byte instead of bfe+cvt), corrected by
//    128*sum(p*scale) in the epilogue.
//  - Inline-softmax aggregation, depth-3 software pipelines.
//  - CSR counting sort; self-loops placed during scan; 2 dst-ranged scatters.
//  - Launch-graph compaction: memset folded into prep kernel; scan_b folded
//    into scan_c (in-block partial prefix); gemm1 split into 3 chunks
//    co-launched with deg / scatter1 / scatter2 (independent until agg1).
//  - scores2 fused into GEMM2; log_softmax fused into agg2.
// ---------------------------------------------------------------------------

#define LEAKY(e) ((e) >= 0.f ? (e) : 0.2f * (e))

typedef unsigned short ushortT;
typedef unsigned int uintT;
typedef unsigned char ucharT;
typedef __attribute__((ext_vector_type(8))) short short8;
typedef __attribute__((ext_vector_type(4))) float float4v;

static __device__ __forceinline__ float bflo(uintT u) {
    return __uint_as_float(u << 16);
}
static __device__ __forceinline__ float bfhi(uintT u) {
    return __uint_as_float(u & 0xffff0000u);
}
static __device__ __forceinline__ ushortT f2bf(float f) {
    __hip_bfloat16 h = __float2bfloat16(f);   // RNE
    return *reinterpret_cast<ushortT*>(&h);
}
static __device__ __forceinline__ uintT pk(float a, float b) {
    return (uintT)f2bf(a) | ((uintT)f2bf(b) << 16);
}
static __device__ __forceinline__ float ub(uintT u, int k) {   // unsigned byte k
    return (float)((u >> (8 * k)) & 0xffu);                    // -> v_cvt_f32_ubyteN
}

#define PREP_BLOCKS 184

// ---------------- prep: transpose weights to bf16 + score matrix + zero deg
// W1t rows 0..255: storage row s=j*16+n holds W1 col (16n+j) [permuted tiling]
// W1t rows 256..271: Wa (scores);  W2t: 48 x 256 (cols 40..47 zero)
// blocks >= PREP_BLOCKS zero the degree array (replaces hipMemsetAsync).
__global__ __launch_bounds__(256) void k_prep_zero(const float* __restrict__ W1,
                                                   const float* __restrict__ W2,
                                                   const float* __restrict__ a1s,
                                                   const float* __restrict__ a1d,
                                                   ushortT* __restrict__ W1t,
                                                   ushortT* __restrict__ W2t,
                                                   int* __restrict__ degz,
                                                   int count4) {
    if (blockIdx.x >= PREP_BLOCKS) {
        int z = (blockIdx.x - PREP_BLOCKS) * 256 + threadIdx.x;
        if (z < count4) ((int4*)degz)[z] = make_int4(0, 0, 0, 0);
        return;
    }
    int t = blockIdx.x * 256 + threadIdx.x;
    if (t < 128 * 256) {
        int k = t >> 8, s = t & 255;
        int c = ((s & 15) << 4) | (s >> 4);
        W1t[s * 128 + k] = f2bf(W1[(size_t)k * 256 + c]);
    } else if (t < 128 * 256 + 48 * 256) {
        int q = t - 128 * 256;
        int k = q / 48, c = q - k * 48;
        W2t[c * 256 + k] = (c < 40) ? f2bf(W2[k * 40 + c]) : (ushortT)0;
    } else if (t < 128 * 256 + 48 * 256 + 2048) {
        int q = t - (128 * 256 + 48 * 256);
        int k = q >> 4, j = q & 15;
        int h = j & 7;
        const float* av = ((j < 8) ? a1s : a1d) + h * 32;
        const float* wr = W1 + (size_t)k * 256 + h * 32;
        float s = 0.f;
        #pragma unroll
        for (int c = 0; c < 32; ++c) s += wr[c] * av[c];
        W1t[(256 + j) * 128 + k] = f2bf(s);
    }
}

// ---------------- GEMM1 worker: x[16,128] @ W1 -> biased-u8 h1i + scale + scores
static __device__ __forceinline__ void dev_gemm1(int slab,
                                                 const float* __restrict__ A,
                                                 const ushortT* __restrict__ Bt,
                                                 ucharT* __restrict__ h1i,
                                                 float* __restrict__ hsc,
                                                 float* __restrict__ s1s,
                                                 float* __restrict__ s1d, int M) {
    int lane = threadIdx.x & 63;
    int r0 = slab * 16;
    if (r0 >= M) return;
    int n = lane & 15, q = lane >> 4;
    const float* arow = A + (size_t)(r0 + n) * 128 + q * 8;
    short8 af[4];
    #pragma unroll
    for (int s = 0; s < 4; ++s) {
        float4 v0 = *(const float4*)(arow + s * 32);
        float4 v1 = *(const float4*)(arow + s * 32 + 4);
        short8 a;
        a[0] = (short)f2bf(v0.x); a[1] = (short)f2bf(v0.y);
        a[2] = (short)f2bf(v0.z); a[3] = (short)f2bf(v0.w);
        a[4] = (short)f2bf(v1.x); a[5] = (short)f2bf(v1.y);
        a[6] = (short)f2bf(v1.z); a[7] = (short)f2bf(v1.w);
        af[s] = a;
    }
    float4v acc[17];
    #pragma unroll
    for (int j = 0; j < 17; ++j) acc[j] = (float4v){0.f, 0.f, 0.f, 0.f};
    #pragma unroll
    for (int s = 0; s < 4; ++s) {
        #pragma unroll
        for (int j = 0; j < 17; ++j) {
            short8 b = *(const short8*)(Bt + (size_t)(j * 16 + n) * 128 + s * 32 + q * 8);
            acc[j] = __builtin_amdgcn_mfma_f32_16x16x32_bf16(af[s], b, acc[j], 0, 0, 0);
        }
    }
    // acc[j][r] = value for row (r0+q*4+r), ORIGINAL col (16n + j)
    float am[4];
    #pragma unroll
    for (int r = 0; r < 4; ++r) {
        float m = 0.f;
        #pragma unroll
        for (int j = 0; j < 16; ++j) m = fmaxf(m, fabsf(acc[j][r]));
        am[r] = m;
    }
    #pragma unroll
    for (int off = 1; off < 16; off <<= 1) {
        #pragma unroll
        for (int r = 0; r < 4; ++r) am[r] = fmaxf(am[r], __shfl_xor(am[r], off, 64));
    }
    #pragma unroll
    for (int r = 0; r < 4; ++r) {
        int row = r0 + q * 4 + r;
        float m = am[r];
        float si = (m > 0.f) ? 127.f / m : 0.f;
        uintT wd[4];
        #pragma unroll
        for (int wq = 0; wq < 4; ++wq) {
            uintT p4 = 0;
            #pragma unroll
            for (int b = 0; b < 4; ++b) {
                int j = wq * 4 + b;
                int qv = (int)rintf(acc[j][r] * si) + 128;   // biased uint8
                p4 |= ((uintT)(qv & 0xff)) << (8 * b);
            }
            wd[wq] = p4;
        }
        uint4 o = make_uint4(wd[0], wd[1], wd[2], wd[3]);
        *(uint4*)(h1i + (size_t)row * 256 + n * 16) = o;
        if (n == 0) hsc[row] = m * (1.f / 127.f);
        float vv = acc[16][r];
        if (n < 8) s1s[(size_t)row * 8 + n] = vv;
        else       s1d[(size_t)row * 8 + (n - 8)] = vv;
    }
}

// ---------------- fused: degree count (+ gemm1 chunk) ----------------------
__global__ __launch_bounds__(256) void k_deg_g1(const int* __restrict__ ei, int E,
                                                int* __restrict__ deg,
                                                const float* __restrict__ A,
                                                const ushortT* __restrict__ Bt,
                                                ucharT* __restrict__ h1i,
                                                float* __restrict__ hsc,
                                                float* __restrict__ s1s,
                                                float* __restrict__ s1d,
                                                int M, int nPrim, int slabBase) {
    if (blockIdx.x >= nPrim) {
        int wave = threadIdx.x >> 6;
        int slab = slabBase + (blockIdx.x - nPrim) * 4 + wave;
        dev_gemm1(slab, A, Bt, h1i, hsc, s1s, s1d, M);
        return;
    }
    int e4 = (blockIdx.x * 256 + threadIdx.x) * 4;
    if (e4 + 3 < E) {
        int4 d = *(const int4*)(ei + E + e4);
        atomicAdd(&deg[d.x], 1);
        atomicAdd(&deg[d.y], 1);
        atomicAdd(&deg[d.z], 1);
        atomicAdd(&deg[d.w], 1);
    } else {
        for (int e = e4; e < E; ++e) atomicAdd(&deg[ei[E + e]], 1);
    }
}

// ---------------- scan stage A (per-1024-block inclusive + block totals) ---
__global__ __launch_bounds__(1024) void k_scan_a(const int* __restrict__ deg,
                                                 int* __restrict__ tmp,
                                                 int* __restrict__ part, int n) {
    __shared__ int wsum[16];
    int t = threadIdx.x, lane = t & 63, wv = t >> 6;
    int i = blockIdx.x * 1024 + t;
    int v = (i < n) ? (deg[i] + 1) : 0;   // +1 = self loop
    int incl = v;
    #pragma unroll
    for (int off = 1; off < 64; off <<= 1) {
        int u = __shfl_up(incl, off, 64);
        if (lane >= off) incl += u;
    }
    if (lane == 63) wsum[wv] = incl;
    __syncthreads();
    if (wv == 0) {
        int s = (lane < 16) ? wsum[lane] : 0;
        #pragma unroll
        for (int off = 1; off < 16; off <<= 1) {
            int u = __shfl_up(s, off, 64);
            if (lane >= off) s += u;
        }
        if (lane < 16) wsum[lane] = s;
    }
    __syncthreads();
    int g = incl + (wv ? wsum[wv - 1] : 0);
    if (i < n) tmp[i] = g;
    if (t == 1023) part[blockIdx.x] = g;
}

// ---------------- scan stage C (scan_b folded in: in-block partial prefix) -
__global__ __launch_bounds__(256) void k_scan_c2(const int* __restrict__ deg,
                                                 const int* __restrict__ tmp,
                                                 const int* __restrict__ part,
                                                 int* __restrict__ rowptr,
                                                 int* __restrict__ cursor,
                                                 int* __restrict__ csr_src, int n) {
    __shared__ int s_off;
    int t = threadIdx.x;
    int b = (int)(blockIdx.x >> 2);     // 256-thread block covers one 1024-chunk quarter
    if (t < 64) {
        int p = 0;
        for (int j = t; j < b; j += 64) p += part[j];   // b <= ~98: at most 2 iters
        #pragma unroll
        for (int o = 32; o; o >>= 1) p += __shfl_xor(p, o, 64);
        if (t == 0) s_off = p;
    }
    __syncthreads();
    int off = s_off;
    int i = blockIdx.x * 256 + t;
    if (i >= n) return;
    int incl = tmp[i] + off;
    rowptr[i + 1] = incl;
    int start = incl - (deg[i] + 1);
    csr_src[start] = i;        // self loop pre-placed
    cursor[i] = start + 1;
    if (i == 0) rowptr[0] = 0;
}

// ---------------- fused: dst-ranged scatter (+ gemm1 chunk) ----------------
__global__ __launch_bounds__(256) void k_scat_g1(const int* __restrict__ ei, int E,
                                                 int* __restrict__ cursor,
                                                 int* __restrict__ csr_src,
                                                 int lo, int hi,
                                                 const float* __restrict__ A,
                                                 const ushortT* __restrict__ Bt,
                                                 ucharT* __restrict__ h1i,
                                                 float* __restrict__ hsc,
                                                 float* __restrict__ s1s,
                                                 float* __restrict__ s1d,
                                                 int M, int nPrim, int slabBase) {
    if (blockIdx.x >= nPrim) {
        int wave = threadIdx.x >> 6;
        int slab = slabBase + (blockIdx.x - nPrim) * 4 + wave;
        dev_gemm1(slab, A, Bt, h1i, hsc, s1s, s1d, M);
        return;
    }
    int e = blockIdx.x * 256 + threadIdx.x;
    if (e >= E) return;
    int dst = ei[E + e];
    if (dst < lo || dst >= hi) return;
    int pos = atomicAdd(&cursor[dst], 1);
    csr_src[pos] = ei[e];
}

// ---------------- layer-1 aggregation: biased-u8 values, 2 slots x depth-3 -
__global__ __launch_bounds__(256) void k_agg1(const ucharT* __restrict__ h1i,
                                              const float* __restrict__ hsc,
                                              const float* __restrict__ ssrc,
                                              const float* __restrict__ sdst,
                                              const int* __restrict__ rowptr,
                                              const int* __restrict__ csr_src,
                                              const float* __restrict__ b1,
                                              ushortT* __restrict__ out1, int N) {
    int lane = threadIdx.x & 63;
    int wid = threadIdx.x >> 6;
    int n = blockIdx.x * 4 + wid;
    if (n >= N) return;
    int slot = lane >> 5;        // edge parity
    int cl = lane & 31;          // 8 channels each (u8)
    int head = cl >> 2;
    int beg = rowptr[n], end = rowptr[n + 1];
    float sdn = sdst[(size_t)n * 8 + head];
    const ucharT* hb = h1i + cl * 8;
    float a0 = 0.f, a1 = 0.f, a2 = 0.f, a3 = 0.f;
    float a4 = 0.f, a5 = 0.f, a6 = 0.f, a7 = 0.f, l = 0.f, sps = 0.f;
    int i0 = beg + slot;
    float sv0 = 0.f, sv1 = 0.f, sv2 = 0.f;
    float sc0 = 0.f, sc1 = 0.f, sc2 = 0.f;
    uint2 v0 = make_uint2(0u, 0u), v1 = v0, v2 = v0;
    if (i0 < end) {
        int s = csr_src[i0];
        sv0 = ssrc[(size_t)s * 8 + head]; sc0 = hsc[s];
        v0 = *(const uint2*)(hb + (size_t)s * 256);
    }
    if (i0 + 2 < end) {
        int s = csr_src[i0 + 2];
        sv1 = ssrc[(size_t)s * 8 + head]; sc1 = hsc[s];
        v1 = *(const uint2*)(hb + (size_t)s * 256);
    }
    if (i0 + 4 < end) {
        int s = csr_src[i0 + 4];
        sv2 = ssrc[(size_t)s * 8 + head]; sc2 = hsc[s];
        v2 = *(const uint2*)(hb + (size_t)s * 256);
    }
    for (int idx = i0; idx < end; idx += 2) {
        float sv = sv0, sc = sc0; uint2 v = v0;
        sv0 = sv1; sc0 = sc1; v0 = v1;
        sv1 = sv2; sc1 = sc2; v1 = v2;
        int i6 = idx + 6;
        if (i6 < end) {
            int s = csr_src[i6];
            sv2 = ssrc[(size_t)s * 8 + head]; sc2 = hsc[s];
            v2 = *(const uint2*)(hb + (size_t)s * 256);
        }
        float p = __expf(LEAKY(sv + sdn));
        l += p;
        float ps = p * sc;
        sps += ps;
        a0 += ps * ub(v.x, 0); a1 += ps * ub(v.x, 1);
        a2 += ps * ub(v.x, 2); a3 += ps * ub(v.x, 3);
        a4 += ps * ub(v.y, 0); a5 += ps * ub(v.y, 1);
        a6 += ps * ub(v.y, 2); a7 += ps * ub(v.y, 3);
    }
    a0 += __shfl_xor(a0, 32, 64); a1 += __shfl_xor(a1, 32, 64);
    a2 += __shfl_xor(a2, 32, 64); a3 += __shfl_xor(a3, 32, 64);
    a4 += __shfl_xor(a4, 32, 64); a5 += __shfl_xor(a5, 32, 64);
    a6 += __shfl_xor(a6, 32, 64); a7 += __shfl_xor(a7, 32, 64);
    l += __shfl_xor(l, 32, 64);
    sps += __shfl_xor(sps, 32, 64);
    if (slot == 0) {
        float inv = 1.f / l;
        float adj = 128.f * sps;            // undo the uint8 bias
        const float4 bb0 = *(const float4*)(b1 + cl * 8);
        const float4 bb1 = *(const float4*)(b1 + cl * 8 + 4);
        uint4 o;
        o.x = pk(fmaxf((a0 - adj) * inv + bb0.x, 0.f), fmaxf((a1 - adj) * inv + bb0.y, 0.f));
        o.y = pk(fmaxf((a2 - adj) * inv + bb0.z, 0.f), fmaxf((a3 - adj) * inv + bb0.w, 0.f));
        o.z = pk(fmaxf((a4 - adj) * inv + bb1.x, 0.f), fmaxf((a5 - adj) * inv + bb1.y, 0.f));
        o.w = pk(fmaxf((a6 - adj) * inv + bb1.z, 0.f), fmaxf((a7 - adj) * inv + bb1.w, 0.f));
        *(uint4*)(out1 + (size_t)n * 256 + cl * 8) = o;
    }
}

// ---------------- GEMM2: out1b[M,256] @ W2 -> bf16 h2b[M,40] + scores2 -----
__global__ __launch_bounds__(256) void k_gemm2(const ushortT* __restrict__ X,
                                               const ushortT* __restrict__ Bt,
                                               const float* __restrict__ a2s,
                                               const float* __restrict__ a2d,
                                               ushortT* __restrict__ H2,
                                               float* __restrict__ s2s,
                                               float* __restrict__ s2d, int M) {
    int lane = threadIdx.x & 63, wave = threadIdx.x >> 6;
    int slab = blockIdx.x * 4 + wave;
    int r0 = slab * 16;
    if (r0 >= M) return;
    int n = lane & 15, q = lane >> 4;
    const ushortT* xrow = X + (size_t)(r0 + n) * 256 + q * 8;
    float4v acc[3];
    #pragma unroll
    for (int j = 0; j < 3; ++j) acc[j] = (float4v){0.f, 0.f, 0.f, 0.f};
    #pragma unroll
    for (int s = 0; s < 8; ++s) {
        short8 a = *(const short8*)(xrow + s * 32);
        #pragma unroll
        for (int j = 0; j < 3; ++j) {
            short8 b = *(const short8*)(Bt + (size_t)(j * 16 + n) * 256 + s * 32 + q * 8);
            acc[j] = __builtin_amdgcn_mfma_f32_16x16x32_bf16(a, b, acc[j], 0, 0, 0);
        }
    }
    float asv[3], adv[3];
    #pragma unroll
    for (int j = 0; j < 3; ++j) {
        int col = j * 16 + n;
        asv[j] = (col < 40) ? a2s[col] : 0.f;
        adv[j] = (col < 40) ? a2d[col] : 0.f;
    }
    float us[4], ud[4];
    #pragma unroll
    for (int r = 0; r < 4; ++r) {
        us[r] = acc[0][r] * asv[0] + acc[1][r] * asv[1] + acc[2][r] * asv[2];
        ud[r] = acc[0][r] * adv[0] + acc[1][r] * adv[1] + acc[2][r] * adv[2];
    }
    #pragma unroll
    for (int off = 1; off < 16; off <<= 1) {
        #pragma unroll
        for (int r = 0; r < 4; ++r) {
            us[r] += __shfl_xor(us[r], off, 64);
            ud[r] += __shfl_xor(ud[r], off, 64);
        }
    }
    #pragma unroll
    for (int j = 0; j < 3; ++j) {
        int col = j * 16 + n;
        if (col < 40) {
            #pragma unroll
            for (int r = 0; r < 4; ++r)
                H2[(size_t)(r0 + q * 4 + r) * 40 + col] = f2bf(acc[j][r]);
        }
    }
    if (n == 0) {
        #pragma unroll
        for (int r = 0; r < 4; ++r) {
            int row = r0 + q * 4 + r;
            s2s[row] = us[r];
            s2d[row] = ud[r];
        }
    }
}

// ---------------- layer-2 aggregation + log_softmax (depth-3 pipeline) -----
__global__ __launch_bounds__(256) void k_agg2lsm(const ushortT* __restrict__ h2,
                                                 const float* __restrict__ ss,
                                                 const float* __restrict__ sd,
                                                 const int* __restrict__ rowptr,
                                                 const int* __restrict__ csr_src,
                                                 const float* __restrict__ b2,
                                                 float* __restrict__ out, int N) {
    int lane = threadIdx.x & 63;
    int wid = threadIdx.x >> 6;
    int n = blockIdx.x * 4 + wid;
    if (n >= N) return;
    int el = lane / 10;
    int cl = lane - el * 10;
    int beg = rowptr[n], end = rowptr[n + 1];
    float sdn = sd[n];
    float a0 = 0.f, a1 = 0.f, a2 = 0.f, a3 = 0.f, l = 0.f;
    if (el < 6) {
        int ia = beg + el;
        float sv0 = 0.f, sv1 = 0.f, sv2 = 0.f;
        uint2 v0 = make_uint2(0u, 0u), v1 = v0, v2 = v0;
        if (ia < end) {
            int s = csr_src[ia];
            sv0 = ss[s];
            v0 = *(const uint2*)(h2 + (size_t)s * 40 + cl * 4);
        }
        if (ia + 6 < end) {
            int s = csr_src[ia + 6];
            sv1 = ss[s];
            v1 = *(const uint2*)(h2 + (size_t)s * 40 + cl * 4);
        }
        if (ia + 12 < end) {
            int s = csr_src[ia + 12];
            sv2 = ss[s];
            v2 = *(const uint2*)(h2 + (size_t)s * 40 + cl * 4);
        }
        for (int idx = ia; idx < end; idx += 6) {
            float sv = sv0; uint2 v = v0;
            sv0 = sv1; v0 = v1;
            sv1 = sv2; v1 = v2;
            int i3 = idx + 18;
            if (i3 < end) {
                int s = csr_src[i3];
                sv2 = ss[s];
                v2 = *(const uint2*)(h2 + (size_t)s * 40 + cl * 4);
            }
            float p = __expf(LEAKY(sv + sdn));
            l += p;
            a0 += p * bflo(v.x); a1 += p * bfhi(v.x);
            a2 += p * bflo(v.y); a3 += p * bfhi(v.y);
        }
    }
    // reduce the 6 slots into lanes 0..9
    float t0 = 0.f, t1 = 0.f, t2 = 0.f, t3 = 0.f, lt = 0.f;
    #pragma unroll
    for (int k = 0; k < 6; ++k) {
        int sl = cl + 10 * k;
        t0 += __shfl(a0, sl, 64);
        t1 += __shfl(a1, sl, 64);
        t2 += __shfl(a2, sl, 64);
        t3 += __shfl(a3, sl, 64);
        if (cl == 0) lt += __shfl(l, sl, 64);
    }
    lt = __shfl(lt, 0, 64);
    float inv = 1.f / lt;
    float o0 = t0 * inv + b2[cl * 4 + 0];
    float o1 = t1 * inv + b2[cl * 4 + 1];
    float o2 = t2 * inv + b2[cl * 4 + 2];
    float o3 = t3 * inv + b2[cl * 4 + 3];
    float lm = (lane < 10) ? fmaxf(fmaxf(o0, o1), fmaxf(o2, o3)) : -INFINITY;
    #pragma unroll
    for (int off = 32; off; off >>= 1) lm = fmaxf(lm, __shfl_xor(lm, off, 64));
    float le = (lane < 10)
        ? __expf(o0 - lm) + __expf(o1 - lm) + __expf(o2 - lm) + __expf(o3 - lm)
        : 0.f;
    #pragma unroll
    for (int off = 32; off; off >>= 1) le += __shfl_xor(le, off, 64);
    float ls = lm + logf(le);
    if (lane < 10) {
        float4 w = make_float4(o0 - ls, o1 - ls, o2 - ls, o3 - ls);
        *(float4*)(out + (size_t)n * 40 + cl * 4) = w;
    }
}

// ---------------------------------------------------------------------------
extern "C" void kernel_launch(void* const* d_in, const int* in_sizes, int n_in,
                              void* d_out, int out_size, void* d_ws, size_t ws_size,
                              hipStream_t stream) {
    const float* x   = (const float*)d_in[0];
    const int*   ei  = (const int*)d_in[1];
    const float* W1  = (const float*)d_in[2];
    const float* a1s = (const float*)d_in[3];
    const float* a1d = (const float*)d_in[4];
    const float* b1  = (const float*)d_in[5];
    const float* W2  = (const float*)d_in[6];
    const float* a2s = (const float*)d_in[7];
    const float* a2d = (const float*)d_in[8];
    const float* b2  = (const float*)d_in[9];
    float* out = (float*)d_out;

    const int N = in_sizes[0] / 128;   // 100000
    const int E = in_sizes[1] / 2;     // 1600000
    const int ET = E + N;

    // ---- workspace layout ----
    char* w = (char*)d_ws;
    ucharT* h1i = (ucharT*)w;                             // N*256 u8 (25.6 MB)
    float* hsc  = (float*)(w + (size_t)N * 256);          // N f32 row scales
    ushortT* out1b = (ushortT*)(w + (size_t)N * 256 + (size_t)N * 4);  // N*256 bf16
    float* s1s  = (float*)(out1b + (size_t)N * 256);      // N*8
    float* s1d  = s1s + (size_t)N * 8;
    int* i_deg = (int*)(s1d + (size_t)N * 8);
    int* i_row = i_deg + (N + 16);
    int* i_cur = i_row + (N + 16);
    int* i_tmp = i_cur + (N + 16);
    int* i_par = i_tmp + (N + 16);
    int* i_csr = i_par + 2048;                            // ET ints
    ushortT* W1t = (ushortT*)(i_csr + ET);                // 272*128 bf16
    ushortT* W2t = W1t + 272 * 128;                       // 48*256 bf16
    // layer-2 overlays h1i (dead after k_agg1)
    ushortT* h2b = (ushortT*)w;                           // N*40 bf16 (8 MB)
    float* s2s = (float*)(w + (size_t)N * 40 * 2);        // N
    float* s2d = s2s + N;                                 // N

    const int nb4 = (N + 3) / 4;
    const int nbs = (N + 1023) / 1024;
    const int nbG = (N / 16 + 3) / 4;            // gemm1 blocks (4 waves x 16 rows)
    const int CH  = (nbG + 2) / 3;               // gemm1 chunk (blocks)
    const int degB  = (E / 4 + 255) / 256;
    const int scatB = (E + 255) / 256;
    const int count4 = (N + 16) / 4;
    const int zeroB = (count4 + 255) / 256;

    // ---- L0: weight prep + deg zeroing ----
    k_prep_zero<<<PREP_BLOCKS + zeroB, 256, 0, stream>>>(W1, W2, a1s, a1d, W1t, W2t,
                                                         i_deg, count4);
    // ---- L1: degree count ∥ gemm1 chunk 0 ----
    k_deg_g1<<<degB + CH, 256, 0, stream>>>(ei, E, i_deg, x, W1t, h1i, hsc, s1s, s1d,
                                            N, degB, 0);
    // ---- L2/L3: scan (scan_b folded into scan_c) ----
    k_scan_a<<<nbs, 1024, 0, stream>>>(i_deg, i_tmp, i_par, N);
    k_scan_c2<<<(N + 255) / 256, 256, 0, stream>>>(i_deg, i_tmp, i_par, i_row, i_cur,
                                                   i_csr, N);
    // ---- L4/L5: 2 dst-ranged scatter passes ∥ gemm1 chunks 1,2 ----
    {
        int step = (N + 1) / 2;
        k_scat_g1<<<scatB + CH, 256, 0, stream>>>(ei, E, i_cur, i_csr, 0, step,
                                                  x, W1t, h1i, hsc, s1s, s1d,
                                                  N, scatB, CH * 4);
        k_scat_g1<<<scatB + CH, 256, 0, stream>>>(ei, E, i_cur, i_csr, step, N,
                                                  x, W1t, h1i, hsc, s1s, s1d,
                                                  N, scatB, CH * 8);
    }

    // ---- layer 1 aggregation ----
    k_agg1<<<nb4, 256, 0, stream>>>(h1i, hsc, s1s, s1d, i_row, i_csr, b1, out1b, N);

    // ---- layer 2 ----
    k_gemm2<<<nbG, 256, 0, stream>>>(out1b, W2t, a2s, a2d, h2b, s2s, s2d, N);
    k_agg2lsm<<<nb4, 256, 0, stream>>>(h2b, s2s, s2d, i_row, i_csr, b2, out, N);
}

// Round 3
// 519.078 us; speedup vs baseline: 1.0514x; 1.0371x over previous
//
#include <hip/hip_runtime.h>
#include <hip/hip_bf16.h>
#include <cmath>

// ---------------------------------------------------------------------------
// GAT 2-layer forward.
//  - LDS-free MFMA GEMMs (A direct global->reg, B pre-transposed bf16).
//  - scores1 fused into GEMM1 (extra 16 output cols via Wa = W1 @ blockdiag(a)).
//  - h1 stored BIASED UINT8 (q+128) with per-row scale -> agg1 unpacks with
//    v_cvt_f32_ubyte{0..3}, corrected by 128*sum(p*scale) in the epilogue.
//  - agg1: 16 ch/lane, 4 edges/wave, rotation-free 3x-unrolled pipeline
//    (bounded for-loop, predicated stages), packed v_pk_fma_f32 accumulate,
//    fma-form leaky.
//  - CSR counting sort; self-loops placed during scan; 2 dst-ranged scatters.
//  - Launch-graph compaction: memset folded into prep kernel; scan_b folded
//    into scan_c; gemm1 split into 3 chunks co-launched with deg/scatters.
//  - scores2 fused into GEMM2; log_softmax fused into agg2 (same unroll).
// ---------------------------------------------------------------------------

typedef unsigned short ushortT;
typedef unsigned int uintT;
typedef unsigned char ucharT;
typedef __attribute__((ext_vector_type(8))) short short8;
typedef __attribute__((ext_vector_type(4))) float float4v;
typedef __attribute__((ext_vector_type(2))) float float2v;

static __device__ __forceinline__ float bflo(uintT u) {
    return __uint_as_float(u << 16);
}
static __device__ __forceinline__ float bfhi(uintT u) {
    return __uint_as_float(u & 0xffff0000u);
}
static __device__ __forceinline__ ushortT f2bf(float f) {
    __hip_bfloat16 h = __float2bfloat16(f);   // RNE
    return *reinterpret_cast<ushortT*>(&h);
}
static __device__ __forceinline__ uintT pk(float a, float b) {
    return (uintT)f2bf(a) | ((uintT)f2bf(b) << 16);
}
static __device__ __forceinline__ float ub(uintT u, int k) {   // unsigned byte k
    return (float)((u >> (8 * k)) & 0xffu);                    // -> v_cvt_f32_ubyteN
}
// leaky: e>=0 -> e ; e<0 -> 0.2e.  0.6e + 0.4|e| (2 VALU, abs = modifier)
static __device__ __forceinline__ float lrelu(float e) {
    return 0.6f * e + 0.4f * fabsf(e);
}

#define PREP_BLOCKS 184

// ---------------- prep: transpose weights to bf16 + score matrix + zero deg
__global__ __launch_bounds__(256) void k_prep_zero(const float* __restrict__ W1,
                                                   const float* __restrict__ W2,
                                                   const float* __restrict__ a1s,
                                                   const float* __restrict__ a1d,
                                                   ushortT* __restrict__ W1t,
                                                   ushortT* __restrict__ W2t,
                                                   int* __restrict__ degz,
                                                   int count4) {
    if (blockIdx.x >= PREP_BLOCKS) {
        int z = (blockIdx.x - PREP_BLOCKS) * 256 + threadIdx.x;
        if (z < count4) ((int4*)degz)[z] = make_int4(0, 0, 0, 0);
        return;
    }
    int t = blockIdx.x * 256 + threadIdx.x;
    if (t < 128 * 256) {
        int k = t >> 8, s = t & 255;
        int c = ((s & 15) << 4) | (s >> 4);
        W1t[s * 128 + k] = f2bf(W1[(size_t)k * 256 + c]);
    } else if (t < 128 * 256 + 48 * 256) {
        int q = t - 128 * 256;
        int k = q / 48, c = q - k * 48;
        W2t[c * 256 + k] = (c < 40) ? f2bf(W2[k * 40 + c]) : (ushortT)0;
    } else if (t < 128 * 256 + 48 * 256 + 2048) {
        int q = t - (128 * 256 + 48 * 256);
        int k = q >> 4, j = q & 15;
        int h = j & 7;
        const float* av = ((j < 8) ? a1s : a1d) + h * 32;
        const float* wr = W1 + (size_t)k * 256 + h * 32;
        float s = 0.f;
        #pragma unroll
        for (int c = 0; c < 32; ++c) s += wr[c] * av[c];
        W1t[(256 + j) * 128 + k] = f2bf(s);
    }
}

// ---------------- GEMM1 worker: x[16,128] @ W1 -> biased-u8 h1i + scale + scores
static __device__ __forceinline__ void dev_gemm1(int slab,
                                                 const float* __restrict__ A,
                                                 const ushortT* __restrict__ Bt,
                                                 ucharT* __restrict__ h1i,
                                                 float* __restrict__ hsc,
                                                 float* __restrict__ s1s,
                                                 float* __restrict__ s1d, int M) {
    int lane = threadIdx.x & 63;
    int r0 = slab * 16;
    if (r0 >= M) return;
    int n = lane & 15, q = lane >> 4;
    const float* arow = A + (size_t)(r0 + n) * 128 + q * 8;
    short8 af[4];
    #pragma unroll
    for (int s = 0; s < 4; ++s) {
        float4 v0 = *(const float4*)(arow + s * 32);
        float4 v1 = *(const float4*)(arow + s * 32 + 4);
        short8 a;
        a[0] = (short)f2bf(v0.x); a[1] = (short)f2bf(v0.y);
        a[2] = (short)f2bf(v0.z); a[3] = (short)f2bf(v0.w);
        a[4] = (short)f2bf(v1.x); a[5] = (short)f2bf(v1.y);
        a[6] = (short)f2bf(v1.z); a[7] = (short)f2bf(v1.w);
        af[s] = a;
    }
    float4v acc[17];
    #pragma unroll
    for (int j = 0; j < 17; ++j) acc[j] = (float4v){0.f, 0.f, 0.f, 0.f};
    #pragma unroll
    for (int s = 0; s < 4; ++s) {
        #pragma unroll
        for (int j = 0; j < 17; ++j) {
            short8 b = *(const short8*)(Bt + (size_t)(j * 16 + n) * 128 + s * 32 + q * 8);
            acc[j] = __builtin_amdgcn_mfma_f32_16x16x32_bf16(af[s], b, acc[j], 0, 0, 0);
        }
    }
    float am[4];
    #pragma unroll
    for (int r = 0; r < 4; ++r) {
        float m = 0.f;
        #pragma unroll
        for (int j = 0; j < 16; ++j) m = fmaxf(m, fabsf(acc[j][r]));
        am[r] = m;
    }
    #pragma unroll
    for (int off = 1; off < 16; off <<= 1) {
        #pragma unroll
        for (int r = 0; r < 4; ++r) am[r] = fmaxf(am[r], __shfl_xor(am[r], off, 64));
    }
    #pragma unroll
    for (int r = 0; r < 4; ++r) {
        int row = r0 + q * 4 + r;
        float m = am[r];
        float si = (m > 0.f) ? 127.f / m : 0.f;
        uintT wd[4];
        #pragma unroll
        for (int wq = 0; wq < 4; ++wq) {
            uintT p4 = 0;
            #pragma unroll
            for (int b = 0; b < 4; ++b) {
                int j = wq * 4 + b;
                int qv = (int)rintf(acc[j][r] * si) + 128;   // biased uint8
                p4 |= ((uintT)(qv & 0xff)) << (8 * b);
            }
            wd[wq] = p4;
        }
        uint4 o = make_uint4(wd[0], wd[1], wd[2], wd[3]);
        *(uint4*)(h1i + (size_t)row * 256 + n * 16) = o;
        if (n == 0) hsc[row] = m * (1.f / 127.f);
        float vv = acc[16][r];
        if (n < 8) s1s[(size_t)row * 8 + n] = vv;
        else       s1d[(size_t)row * 8 + (n - 8)] = vv;
    }
}

// ---------------- fused: degree count (+ gemm1 chunk) ----------------------
__global__ __launch_bounds__(256) void k_deg_g1(const int* __restrict__ ei, int E,
                                                int* __restrict__ deg,
                                                const float* __restrict__ A,
                                                const ushortT* __restrict__ Bt,
                                                ucharT* __restrict__ h1i,
                                                float* __restrict__ hsc,
                                                float* __restrict__ s1s,
                                                float* __restrict__ s1d,
                                                int M, int nPrim, int slabBase) {
    if (blockIdx.x >= nPrim) {
        int wave = threadIdx.x >> 6;
        int slab = slabBase + (blockIdx.x - nPrim) * 4 + wave;
        dev_gemm1(slab, A, Bt, h1i, hsc, s1s, s1d, M);
        return;
    }
    int e4 = (blockIdx.x * 256 + threadIdx.x) * 4;
    if (e4 + 3 < E) {
        int4 d = *(const int4*)(ei + E + e4);
        atomicAdd(&deg[d.x], 1);
        atomicAdd(&deg[d.y], 1);
        atomicAdd(&deg[d.z], 1);
        atomicAdd(&deg[d.w], 1);
    } else {
        for (int e = e4; e < E; ++e) atomicAdd(&deg[ei[E + e]], 1);
    }
}

// ---------------- scan stage A ---------------------------------------------
__global__ __launch_bounds__(1024) void k_scan_a(const int* __restrict__ deg,
                                                 int* __restrict__ tmp,
                                                 int* __restrict__ part, int n) {
    __shared__ int wsum[16];
    int t = threadIdx.x, lane = t & 63, wv = t >> 6;
    int i = blockIdx.x * 1024 + t;
    int v = (i < n) ? (deg[i] + 1) : 0;   // +1 = self loop
    int incl = v;
    #pragma unroll
    for (int off = 1; off < 64; off <<= 1) {
        int u = __shfl_up(incl, off, 64);
        if (lane >= off) incl += u;
    }
    if (lane == 63) wsum[wv] = incl;
    __syncthreads();
    if (wv == 0) {
        int s = (lane < 16) ? wsum[lane] : 0;
        #pragma unroll
        for (int off = 1; off < 16; off <<= 1) {
            int u = __shfl_up(s, off, 64);
            if (lane >= off) s += u;
        }
        if (lane < 16) wsum[lane] = s;
    }
    __syncthreads();
    int g = incl + (wv ? wsum[wv - 1] : 0);
    if (i < n) tmp[i] = g;
    if (t == 1023) part[blockIdx.x] = g;
}

// ---------------- scan stage C (scan_b folded in) --------------------------
__global__ __launch_bounds__(256) void k_scan_c2(const int* __restrict__ deg,
                                                 const int* __restrict__ tmp,
                                                 const int* __restrict__ part,
                                                 int* __restrict__ rowptr,
                                                 int* __restrict__ cursor,
                                                 int* __restrict__ csr_src, int n) {
    __shared__ int s_off;
    int t = threadIdx.x;
    int b = (int)(blockIdx.x >> 2);
    if (t < 64) {
        int p = 0;
        for (int j = t; j < b; j += 64) p += part[j];
        #pragma unroll
        for (int o = 32; o; o >>= 1) p += __shfl_xor(p, o, 64);
        if (t == 0) s_off = p;
    }
    __syncthreads();
    int off = s_off;
    int i = blockIdx.x * 256 + t;
    if (i >= n) return;
    int incl = tmp[i] + off;
    rowptr[i + 1] = incl;
    int start = incl - (deg[i] + 1);
    csr_src[start] = i;        // self loop pre-placed
    cursor[i] = start + 1;
    if (i == 0) rowptr[0] = 0;
}

// ---------------- fused: dst-ranged scatter (+ gemm1 chunk) ----------------
__global__ __launch_bounds__(256) void k_scat_g1(const int* __restrict__ ei, int E,
                                                 int* __restrict__ cursor,
                                                 int* __restrict__ csr_src,
                                                 int lo, int hi,
                                                 const float* __restrict__ A,
                                                 const ushortT* __restrict__ Bt,
                                                 ucharT* __restrict__ h1i,
                                                 float* __restrict__ hsc,
                                                 float* __restrict__ s1s,
                                                 float* __restrict__ s1d,
                                                 int M, int nPrim, int slabBase) {
    if (blockIdx.x >= nPrim) {
        int wave = threadIdx.x >> 6;
        int slab = slabBase + (blockIdx.x - nPrim) * 4 + wave;
        dev_gemm1(slab, A, Bt, h1i, hsc, s1s, s1d, M);
        return;
    }
    int e = blockIdx.x * 256 + threadIdx.x;
    if (e >= E) return;
    int dst = ei[E + e];
    if (dst < lo || dst >= hi) return;
    int pos = atomicAdd(&cursor[dst], 1);
    csr_src[pos] = ei[e];
}

// ---------------- layer-1 aggregation --------------------------------------
// 16 ch/lane (uint4), 16 lanes/edge, 4 edges/wave; rotation-free 3x unroll.
struct Edge1 {
    float sv, sc;
    uint4 v;
};

static __device__ __forceinline__ void ld1(Edge1& S, int j, int end,
                                           const int* __restrict__ csr_src,
                                           const float* __restrict__ ssrc,
                                           const float* __restrict__ hsc,
                                           const ucharT* __restrict__ hb, int head) {
    if (j < end) {
        int s = csr_src[j];
        S.sv = ssrc[(size_t)s * 8 + head];
        S.sc = hsc[s];
        S.v = *(const uint4*)(hb + (size_t)s * 256);
    }
}

static __device__ __forceinline__ void ac1(const Edge1& S, float sdn,
                                           float2v* A, float& l, float& sps) {
    float p = __expf(lrelu(S.sv + sdn));
    l += p;
    float ps = p * S.sc;
    sps += ps;
    float2v p2 = {ps, ps};
    uintT w;
    w = S.v.x;
    A[0] += p2 * (float2v){ub(w, 0), ub(w, 1)};
    A[1] += p2 * (float2v){ub(w, 2), ub(w, 3)};
    w = S.v.y;
    A[2] += p2 * (float2v){ub(w, 0), ub(w, 1)};
    A[3] += p2 * (float2v){ub(w, 2), ub(w, 3)};
    w = S.v.z;
    A[4] += p2 * (float2v){ub(w, 0), ub(w, 1)};
    A[5] += p2 * (float2v){ub(w, 2), ub(w, 3)};
    w = S.v.w;
    A[6] += p2 * (float2v){ub(w, 0), ub(w, 1)};
    A[7] += p2 * (float2v){ub(w, 2), ub(w, 3)};
}

__global__ __launch_bounds__(256) void k_agg1(const ucharT* __restrict__ h1i,
                                              const float* __restrict__ hsc,
                                              const float* __restrict__ ssrc,
                                              const float* __restrict__ sdst,
                                              const int* __restrict__ rowptr,
                                              const int* __restrict__ csr_src,
                                              const float* __restrict__ b1,
                                              ushortT* __restrict__ out1, int N) {
    int lane = threadIdx.x & 63;
    int wid = threadIdx.x >> 6;
    int n = blockIdx.x * 4 + wid;
    if (n >= N) return;
    int g = lane >> 4;           // 4 edge slots
    int cl = lane & 15;          // 16 channels each
    int head = cl >> 1;
    int beg = rowptr[n], end = rowptr[n + 1];
    float sdn = sdst[(size_t)n * 8 + head];
    const ucharT* hb = h1i + cl * 16;
    float2v A[8];
    #pragma unroll
    for (int k = 0; k < 8; ++k) A[k] = (float2v){0.f, 0.f};
    float l = 0.f, sps = 0.f;
    int i0 = beg + g;
    if (i0 < end) {
        Edge1 S0, S1, S2;
        S0.sv = S1.sv = S2.sv = 0.f;
        S0.sc = S1.sc = S2.sc = 0.f;
        S0.v = S1.v = S2.v = make_uint4(0u, 0u, 0u, 0u);
        ld1(S0, i0, end, csr_src, ssrc, hsc, hb, head);
        ld1(S1, i0 + 4, end, csr_src, ssrc, hsc, hb, head);
        ld1(S2, i0 + 8, end, csr_src, ssrc, hsc, hb, head);
        for (int idx = i0; idx < end; idx += 12) {
            ac1(S0, sdn, A, l, sps);
            ld1(S0, idx + 12, end, csr_src, ssrc, hsc, hb, head);
            if (idx + 4 < end) {
                ac1(S1, sdn, A, l, sps);
                ld1(S1, idx + 16, end, csr_src, ssrc, hsc, hb, head);
            }
            if (idx + 8 < end) {
                ac1(S2, sdn, A, l, sps);
                ld1(S2, idx + 20, end, csr_src, ssrc, hsc, hb, head);
            }
        }
    }
    // reduce across the 4 edge-slot groups (lanes differing in bits 4,5)
    #pragma unroll
    for (int off = 16; off < 64; off <<= 1) {
        l += __shfl_xor(l, off, 64);
        sps += __shfl_xor(sps, off, 64);
        #pragma unroll
        for (int k = 0; k < 8; ++k) {
            A[k].x += __shfl_xor(A[k].x, off, 64);
            A[k].y += __shfl_xor(A[k].y, off, 64);
        }
    }
    if (g == 0) {
        float inv = 1.f / l;
        float adj = 128.f * sps;            // undo the uint8 bias
        const float4 bb0 = *(const float4*)(b1 + cl * 16);
        const float4 bb1 = *(const float4*)(b1 + cl * 16 + 4);
        const float4 bb2 = *(const float4*)(b1 + cl * 16 + 8);
        const float4 bb3 = *(const float4*)(b1 + cl * 16 + 12);
        float bbf[16] = {bb0.x, bb0.y, bb0.z, bb0.w, bb1.x, bb1.y, bb1.z, bb1.w,
                         bb2.x, bb2.y, bb2.z, bb2.w, bb3.x, bb3.y, bb3.z, bb3.w};
        uintT o[8];
        #pragma unroll
        for (int k = 0; k < 8; ++k) {
            float x0 = fmaxf((A[k].x - adj) * inv + bbf[2 * k], 0.f);
            float x1 = fmaxf((A[k].y - adj) * inv + bbf[2 * k + 1], 0.f);
            o[k] = pk(x0, x1);
        }
        *(uint4*)(out1 + (size_t)n * 256 + cl * 16) =
            make_uint4(o[0], o[1], o[2], o[3]);
        *(uint4*)(out1 + (size_t)n * 256 + cl * 16 + 8) =
            make_uint4(o[4], o[5], o[6], o[7]);
    }
}

// ---------------- GEMM2: out1b[M,256] @ W2 -> bf16 h2b[M,40] + scores2 -----
__global__ __launch_bounds__(256) void k_gemm2(const ushortT* __restrict__ X,
                                               const ushortT* __restrict__ Bt,
                                               const float* __restrict__ a2s,
                                               const float* __restrict__ a2d,
                                               ushortT* __restrict__ H2,
                                               float* __restrict__ s2s,
                                               float* __restrict__ s2d, int M) {
    int lane = threadIdx.x & 63, wave = threadIdx.x >> 6;
    int slab = blockIdx.x * 4 + wave;
    int r0 = slab * 16;
    if (r0 >= M) return;
    int n = lane & 15, q = lane >> 4;
    const ushortT* xrow = X + (size_t)(r0 + n) * 256 + q * 8;
    float4v acc[3];
    #pragma unroll
    for (int j = 0; j < 3; ++j) acc[j] = (float4v){0.f, 0.f, 0.f, 0.f};
    #pragma unroll
    for (int s = 0; s < 8; ++s) {
        short8 a = *(const short8*)(xrow + s * 32);
        #pragma unroll
        for (int j = 0; j < 3; ++j) {
            short8 b = *(const short8*)(Bt + (size_t)(j * 16 + n) * 256 + s * 32 + q * 8);
            acc[j] = __builtin_amdgcn_mfma_f32_16x16x32_bf16(a, b, acc[j], 0, 0, 0);
        }
    }
    float asv[3], adv[3];
    #pragma unroll
    for (int j = 0; j < 3; ++j) {
        int col = j * 16 + n;
        asv[j] = (col < 40) ? a2s[col] : 0.f;
        adv[j] = (col < 40) ? a2d[col] : 0.f;
    }
    float us[4], ud[4];
    #pragma unroll
    for (int r = 0; r < 4; ++r) {
        us[r] = acc[0][r] * asv[0] + acc[1][r] * asv[1] + acc[2][r] * asv[2];
        ud[r] = acc[0][r] * adv[0] + acc[1][r] * adv[1] + acc[2][r] * adv[2];
    }
    #pragma unroll
    for (int off = 1; off < 16; off <<= 1) {
        #pragma unroll
        for (int r = 0; r < 4; ++r) {
            us[r] += __shfl_xor(us[r], off, 64);
            ud[r] += __shfl_xor(ud[r], off, 64);
        }
    }
    #pragma unroll
    for (int j = 0; j < 3; ++j) {
        int col = j * 16 + n;
        if (col < 40) {
            #pragma unroll
            for (int r = 0; r < 4; ++r)
                H2[(size_t)(r0 + q * 4 + r) * 40 + col] = f2bf(acc[j][r]);
        }
    }
    if (n == 0) {
        #pragma unroll
        for (int r = 0; r < 4; ++r) {
            int row = r0 + q * 4 + r;
            s2s[row] = us[r];
            s2d[row] = ud[r];
        }
    }
}

// ---------------- layer-2 aggregation + log_softmax ------------------------
// 6 edge slots x 10 ch-lanes; rotation-free 3x unroll; pk_fma accumulate.
struct Edge2 {
    float sv;
    uint2 v;
};

static __device__ __forceinline__ void ld2(Edge2& S, int j, int end,
                                           const int* __restrict__ csr_src,
                                           const float* __restrict__ ss,
                                           const ushortT* __restrict__ h2, int cl) {
    if (j < end) {
        int s = csr_src[j];
        S.sv = ss[s];
        S.v = *(const uint2*)(h2 + (size_t)s * 40 + cl * 4);
    }
}

static __device__ __forceinline__ void ac2(const Edge2& S, float sdn,
                                           float2v& A01, float2v& A23, float& l) {
    float p = __expf(lrelu(S.sv + sdn));
    l += p;
    float2v p2 = {p, p};
    A01 += p2 * (float2v){bflo(S.v.x), bfhi(S.v.x)};
    A23 += p2 * (float2v){bflo(S.v.y), bfhi(S.v.y)};
}

__global__ __launch_bounds__(256) void k_agg2lsm(const ushortT* __restrict__ h2,
                                                 const float* __restrict__ ss,
                                                 const float* __restrict__ sd,
                                                 const int* __restrict__ rowptr,
                                                 const int* __restrict__ csr_src,
                                                 const float* __restrict__ b2,
                                                 float* __restrict__ out, int N) {
    int lane = threadIdx.x & 63;
    int wid = threadIdx.x >> 6;
    int n = blockIdx.x * 4 + wid;
    if (n >= N) return;
    int el = lane / 10;
    int cl = lane - el * 10;
    int beg = rowptr[n], end = rowptr[n + 1];
    float sdn = sd[n];
    float2v A01 = (float2v){0.f, 0.f}, A23 = (float2v){0.f, 0.f};
    float l = 0.f;
    if (el < 6) {
        int i0 = beg + el;
        if (i0 < end) {
            Edge2 S0, S1, S2;
            S0.sv = S1.sv = S2.sv = 0.f;
            S0.v = S1.v = S2.v = make_uint2(0u, 0u);
            ld2(S0, i0, end, csr_src, ss, h2, cl);
            ld2(S1, i0 + 6, end, csr_src, ss, h2, cl);
            ld2(S2, i0 + 12, end, csr_src, ss, h2, cl);
            for (int idx = i0; idx < end; idx += 18) {
                ac2(S0, sdn, A01, A23, l);
                ld2(S0, idx + 18, end, csr_src, ss, h2, cl);
                if (idx + 6 < end) {
                    ac2(S1, sdn, A01, A23, l);
                    ld2(S1, idx + 24, end, csr_src, ss, h2, cl);
                }
                if (idx + 12 < end) {
                    ac2(S2, sdn, A01, A23, l);
                    ld2(S2, idx + 30, end, csr_src, ss, h2, cl);
                }
            }
        }
    }
    float a0 = A01.x, a1 = A01.y, a2 = A23.x, a3 = A23.y;
    // reduce the 6 slots into lanes 0..9
    float t0 = 0.f, t1 = 0.f, t2 = 0.f, t3 = 0.f, lt = 0.f;
    #pragma unroll
    for (int k = 0; k < 6; ++k) {
        int sl = cl + 10 * k;
        t0 += __shfl(a0, sl, 64);
        t1 += __shfl(a1, sl, 64);
        t2 += __shfl(a2, sl, 64);
        t3 += __shfl(a3, sl, 64);
        if (cl == 0) lt += __shfl(l, sl, 64);
    }
    lt = __shfl(lt, 0, 64);
    float inv = 1.f / lt;
    float o0 = t0 * inv + b2[cl * 4 + 0];
    float o1 = t1 * inv + b2[cl * 4 + 1];
    float o2 = t2 * inv + b2[cl * 4 + 2];
    float o3 = t3 * inv + b2[cl * 4 + 3];
    float lm = (lane < 10) ? fmaxf(fmaxf(o0, o1), fmaxf(o2, o3)) : -INFINITY;
    #pragma unroll
    for (int off = 32; off; off >>= 1) lm = fmaxf(lm, __shfl_xor(lm, off, 64));
    float le = (lane < 10)
        ? __expf(o0 - lm) + __expf(o1 - lm) + __expf(o2 - lm) + __expf(o3 - lm)
        : 0.f;
    #pragma unroll
    for (int off = 32; off; off >>= 1) le += __shfl_xor(le, off, 64);
    float ls = lm + logf(le);
    if (lane < 10) {
        float4 w = make_float4(o0 - ls, o1 - ls, o2 - ls, o3 - ls);
        *(float4*)(out + (size_t)n * 40 + cl * 4) = w;
    }
}

// ---------------------------------------------------------------------------
extern "C" void kernel_launch(void* const* d_in, const int* in_sizes, int n_in,
                              void* d_out, int out_size, void* d_ws, size_t ws_size,
                              hipStream_t stream) {
    const float* x   = (const float*)d_in[0];
    const int*   ei  = (const int*)d_in[1];
    const float* W1  = (const float*)d_in[2];
    const float* a1s = (const float*)d_in[3];
    const float* a1d = (const float*)d_in[4];
    const float* b1  = (const float*)d_in[5];
    const float* W2  = (const float*)d_in[6];
    const float* a2s = (const float*)d_in[7];
    const float* a2d = (const float*)d_in[8];
    const float* b2  = (const float*)d_in[9];
    float* out = (float*)d_out;

    const int N = in_sizes[0] / 128;   // 100000
    const int E = in_sizes[1] / 2;     // 1600000
    const int ET = E + N;

    // ---- workspace layout ----
    char* w = (char*)d_ws;
    ucharT* h1i = (ucharT*)w;                             // N*256 u8 (25.6 MB)
    float* hsc  = (float*)(w + (size_t)N * 256);          // N f32 row scales
    ushortT* out1b = (ushortT*)(w + (size_t)N * 256 + (size_t)N * 4);  // N*256 bf16
    float* s1s  = (float*)(out1b + (size_t)N * 256);      // N*8
    float* s1d  = s1s + (size_t)N * 8;
    int* i_deg = (int*)(s1d + (size_t)N * 8);
    int* i_row = i_deg + (N + 16);
    int* i_cur = i_row + (N + 16);
    int* i_tmp = i_cur + (N + 16);
    int* i_par = i_tmp + (N + 16);
    int* i_csr = i_par + 2048;                            // ET ints
    ushortT* W1t = (ushortT*)(i_csr + ET);                // 272*128 bf16
    ushortT* W2t = W1t + 272 * 128;                       // 48*256 bf16
    // layer-2 overlays h1i (dead after k_agg1)
    ushortT* h2b = (ushortT*)w;                           // N*40 bf16 (8 MB)
    float* s2s = (float*)(w + (size_t)N * 40 * 2);        // N
    float* s2d = s2s + N;                                 // N

    const int nb4 = (N + 3) / 4;
    const int nbs = (N + 1023) / 1024;
    const int nbG = (N / 16 + 3) / 4;            // gemm1 blocks (4 waves x 16 rows)
    const int CH  = (nbG + 2) / 3;               // gemm1 chunk (blocks)
    const int degB  = (E / 4 + 255) / 256;
    const int scatB = (E + 255) / 256;
    const int count4 = (N + 16) / 4;
    const int zeroB = (count4 + 255) / 256;

    // ---- L0: weight prep + deg zeroing ----
    k_prep_zero<<<PREP_BLOCKS + zeroB, 256, 0, stream>>>(W1, W2, a1s, a1d, W1t, W2t,
                                                         i_deg, count4);
    // ---- L1: degree count ∥ gemm1 chunk 0 ----
    k_deg_g1<<<degB + CH, 256, 0, stream>>>(ei, E, i_deg, x, W1t, h1i, hsc, s1s, s1d,
                                            N, degB, 0);
    // ---- L2/L3: scan (scan_b folded into scan_c) ----
    k_scan_a<<<nbs, 1024, 0, stream>>>(i_deg, i_tmp, i_par, N);
    k_scan_c2<<<(N + 255) / 256, 256, 0, stream>>>(i_deg, i_tmp, i_par, i_row, i_cur,
                                                   i_csr, N);
    // ---- L4/L5: 2 dst-ranged scatter passes ∥ gemm1 chunks 1,2 ----
    {
        int step = (N + 1) / 2;
        k_scat_g1<<<scatB + CH, 256, 0, stream>>>(ei, E, i_cur, i_csr, 0, step,
                                                  x, W1t, h1i, hsc, s1s, s1d,
                                                  N, scatB, CH * 4);
        k_scat_g1<<<scatB + CH, 256, 0, stream>>>(ei, E, i_cur, i_csr, step, N,
                                                  x, W1t, h1i, hsc, s1s, s1d,
                                                  N, scatB, CH * 8);
    }

    // ---- layer 1 aggregation ----
    k_agg1<<<nb4, 256, 0, stream>>>(h1i, hsc, s1s, s1d, i_row, i_csr, b1, out1b, N);

    // ---- layer 2 ----
    k_gemm2<<<nbG, 256, 0, stream>>>(out1b, W2t, a2s, a2d, h2b, s2s, s2d, N);
    k_agg2lsm<<<nb4, 256, 0, stream>>>(h2b, s2s, s2d, i_row, i_csr, b2, out, N);
}

// Round 4
// 398.024 us; speedup vs baseline: 1.3711x; 1.3041x over previous
//
#include <hip/hip_runtime.h>
#include <hip/hip_bf16.h>
#include <cmath>

// ---------------------------------------------------------------------------
// GAT 2-layer forward.
//  - LDS-free MFMA GEMMs (A direct global->reg, B pre-transposed bf16).
//  - scores1 fused into GEMM1 (extra 16 output cols via Wa = W1 @ blockdiag(a)).
//  - h1 stored BIASED UINT8 (q+128) with per-row scale; agg1 unpacks with
//    v_cvt_f32_ubyte{0..3}, corrected by 128*sum(p*scale) in the epilogue.
//  - agg1: 16 ch/lane, 4 edges/wave, rotation-free 3x-unrolled pipeline.
//  - CSR build WITHOUT global atomics: bucketed counting sort
//      P1 LDS-histogram -> counts[block][bucket]
//      P2 per-bucket scan across blocks (+ totals)
//      P3 bucket-contiguous placement of packed (src|localdst) via LDS cursors
//      P4 per-bucket CSR finalize (LDS count/scan/place, self-loops included)
//    (replaces deg atomics + 2 global-atomic scatters: those ran at the
//     cross-XCD coherent-atomic rate of ~7/cycle -> ~100us each)
//  - gemm1 split into 3 chunks co-launched with P1/P3/P4.
//  - scores2 fused into GEMM2; log_softmax fused into agg2.
// ---------------------------------------------------------------------------

typedef unsigned short ushortT;
typedef unsigned int uintT;
typedef unsigned char ucharT;
typedef __attribute__((ext_vector_type(8))) short short8;
typedef __attribute__((ext_vector_type(4))) float float4v;
typedef __attribute__((ext_vector_type(2))) float float2v;

static __device__ __forceinline__ float bflo(uintT u) {
    return __uint_as_float(u << 16);
}
static __device__ __forceinline__ float bfhi(uintT u) {
    return __uint_as_float(u & 0xffff0000u);
}
static __device__ __forceinline__ ushortT f2bf(float f) {
    __hip_bfloat16 h = __float2bfloat16(f);   // RNE
    return *reinterpret_cast<ushortT*>(&h);
}
static __device__ __forceinline__ uintT pk(float a, float b) {
    return (uintT)f2bf(a) | ((uintT)f2bf(b) << 16);
}
static __device__ __forceinline__ float ub(uintT u, int k) {   // unsigned byte k
    return (float)((u >> (8 * k)) & 0xffu);                    // -> v_cvt_f32_ubyteN
}
// leaky: e>=0 -> e ; e<0 -> 0.2e.  0.6e + 0.4|e| (2 VALU, abs = modifier)
static __device__ __forceinline__ float lrelu(float e) {
    return 0.6f * e + 0.4f * fabsf(e);
}

#define PREP_BLOCKS 184
#define EPB 4096              // edges per histogram/placement block

// ---------------- prep: transpose weights to bf16 + score matrix -----------
__global__ __launch_bounds__(256) void k_prep(const float* __restrict__ W1,
                                              const float* __restrict__ W2,
                                              const float* __restrict__ a1s,
                                              const float* __restrict__ a1d,
                                              ushortT* __restrict__ W1t,
                                              ushortT* __restrict__ W2t) {
    int t = blockIdx.x * 256 + threadIdx.x;
    if (t < 128 * 256) {
        int k = t >> 8, s = t & 255;
        int c = ((s & 15) << 4) | (s >> 4);
        W1t[s * 128 + k] = f2bf(W1[(size_t)k * 256 + c]);
    } else if (t < 128 * 256 + 48 * 256) {
        int q = t - 128 * 256;
        int k = q / 48, c = q - k * 48;
        W2t[c * 256 + k] = (c < 40) ? f2bf(W2[k * 40 + c]) : (ushortT)0;
    } else if (t < 128 * 256 + 48 * 256 + 2048) {
        int q = t - (128 * 256 + 48 * 256);
        int k = q >> 4, j = q & 15;
        int h = j & 7;
        const float* av = ((j < 8) ? a1s : a1d) + h * 32;
        const float* wr = W1 + (size_t)k * 256 + h * 32;
        float s = 0.f;
        #pragma unroll
        for (int c = 0; c < 32; ++c) s += wr[c] * av[c];
        W1t[(256 + j) * 128 + k] = f2bf(s);
    }
}

// ---------------- GEMM1 worker: x[16,128] @ W1 -> biased-u8 h1i + scale + scores
static __device__ __forceinline__ void dev_gemm1(int slab,
                                                 const float* __restrict__ A,
                                                 const ushortT* __restrict__ Bt,
                                                 ucharT* __restrict__ h1i,
                                                 float* __restrict__ hsc,
                                                 float* __restrict__ s1s,
                                                 float* __restrict__ s1d, int M) {
    int lane = threadIdx.x & 63;
    int r0 = slab * 16;
    if (r0 >= M) return;
    int n = lane & 15, q = lane >> 4;
    const float* arow = A + (size_t)(r0 + n) * 128 + q * 8;
    short8 af[4];
    #pragma unroll
    for (int s = 0; s < 4; ++s) {
        float4 v0 = *(const float4*)(arow + s * 32);
        float4 v1 = *(const float4*)(arow + s * 32 + 4);
        short8 a;
        a[0] = (short)f2bf(v0.x); a[1] = (short)f2bf(v0.y);
        a[2] = (short)f2bf(v0.z); a[3] = (short)f2bf(v0.w);
        a[4] = (short)f2bf(v1.x); a[5] = (short)f2bf(v1.y);
        a[6] = (short)f2bf(v1.z); a[7] = (short)f2bf(v1.w);
        af[s] = a;
    }
    float4v acc[17];
    #pragma unroll
    for (int j = 0; j < 17; ++j) acc[j] = (float4v){0.f, 0.f, 0.f, 0.f};
    #pragma unroll
    for (int s = 0; s < 4; ++s) {
        #pragma unroll
        for (int j = 0; j < 17; ++j) {
            short8 b = *(const short8*)(Bt + (size_t)(j * 16 + n) * 128 + s * 32 + q * 8);
            acc[j] = __builtin_amdgcn_mfma_f32_16x16x32_bf16(af[s], b, acc[j], 0, 0, 0);
        }
    }
    float am[4];
    #pragma unroll
    for (int r = 0; r < 4; ++r) {
        float m = 0.f;
        #pragma unroll
        for (int j = 0; j < 16; ++j) m = fmaxf(m, fabsf(acc[j][r]));
        am[r] = m;
    }
    #pragma unroll
    for (int off = 1; off < 16; off <<= 1) {
        #pragma unroll
        for (int r = 0; r < 4; ++r) am[r] = fmaxf(am[r], __shfl_xor(am[r], off, 64));
    }
    #pragma unroll
    for (int r = 0; r < 4; ++r) {
        int row = r0 + q * 4 + r;
        float m = am[r];
        float si = (m > 0.f) ? 127.f / m : 0.f;
        uintT wd[4];
        #pragma unroll
        for (int wq = 0; wq < 4; ++wq) {
            uintT p4 = 0;
            #pragma unroll
            for (int b = 0; b < 4; ++b) {
                int j = wq * 4 + b;
                int qv = (int)rintf(acc[j][r] * si) + 128;   // biased uint8
                p4 |= ((uintT)(qv & 0xff)) << (8 * b);
            }
            wd[wq] = p4;
        }
        uint4 o = make_uint4(wd[0], wd[1], wd[2], wd[3]);
        *(uint4*)(h1i + (size_t)row * 256 + n * 16) = o;
        if (n == 0) hsc[row] = m * (1.f / 127.f);
        float vv = acc[16][r];
        if (n < 8) s1s[(size_t)row * 8 + n] = vv;
        else       s1d[(size_t)row * 8 + (n - 8)] = vv;
    }
}

// ---------------- P1: per-block LDS histogram over buckets (+ gemm chunk) --
__global__ __launch_bounds__(256) void k_cnt_g1(const int* __restrict__ ei, int E,
                                                int* __restrict__ counts, int nbuck,
                                                const float* __restrict__ A,
                                                const ushortT* __restrict__ Bt,
                                                ucharT* __restrict__ h1i,
                                                float* __restrict__ hsc,
                                                float* __restrict__ s1s,
                                                float* __restrict__ s1d,
                                                int M, int nPrim, int slabBase) {
    if (blockIdx.x >= nPrim) {
        int wave = threadIdx.x >> 6;
        int slab = slabBase + (blockIdx.x - nPrim) * 4 + wave;
        dev_gemm1(slab, A, Bt, h1i, hsc, s1s, s1d, M);
        return;
    }
    __shared__ int h[1024];
    int t = threadIdx.x;
    for (int i = t; i < nbuck; i += 256) h[i] = 0;
    __syncthreads();
    int base = blockIdx.x * EPB;
    #pragma unroll
    for (int r = 0; r < 4; ++r) {
        int i4 = base + (r * 256 + t) * 4;
        if (i4 + 3 < E) {
            int4 d = *(const int4*)(ei + E + i4);
            atomicAdd(&h[d.x >> 7], 1);
            atomicAdd(&h[d.y >> 7], 1);
            atomicAdd(&h[d.z >> 7], 1);
            atomicAdd(&h[d.w >> 7], 1);
        } else {
            for (int j = i4; j < E; ++j) atomicAdd(&h[ei[E + j] >> 7], 1);
        }
    }
    __syncthreads();
    int* crow = counts + (size_t)blockIdx.x * nbuck;
    for (int i = t; i < nbuck; i += 256) crow[i] = h[i];
}

// ---------------- P2: per-bucket exclusive scan across blocks --------------
__global__ __launch_bounds__(256) void k_scan_cols(int* __restrict__ counts,
                                                   int* __restrict__ totals,
                                                   int nb1, int nbuck) {
    __shared__ int wsum[4];
    int k = blockIdx.x;
    int t = threadIdx.x, lane = t & 63, wv = t >> 6;
    int e0 = 2 * t, e1 = 2 * t + 1;
    int v0 = (e0 < nb1) ? counts[(size_t)e0 * nbuck + k] : 0;
    int v1 = (e1 < nb1) ? counts[(size_t)e1 * nbuck + k] : 0;
    int s = v0 + v1;
    int incl = s;
    #pragma unroll
    for (int off = 1; off < 64; off <<= 1) {
        int u = __shfl_up(incl, off, 64);
        if (lane >= off) incl += u;
    }
    if (lane == 63) wsum[wv] = incl;
    __syncthreads();
    int add = 0;
    if (wv > 0) add += wsum[0];
    if (wv > 1) add += wsum[1];
    if (wv > 2) add += wsum[2];
    incl += add;
    int excl = incl - s;
    if (e0 < nb1) counts[(size_t)e0 * nbuck + k] = excl;
    if (e1 < nb1) counts[(size_t)e1 * nbuck + k] = excl + v0;
    if (t == 255) totals[k] = incl;
}

// ---------------- P3: bucket-contiguous placement (+ gemm chunk) -----------
// tmp[pos] = src | (localdst << 17);  pos from LDS cursor per bucket.
__global__ __launch_bounds__(256) void k_place_g1(const int* __restrict__ ei, int E,
                                                  const int* __restrict__ counts,
                                                  const int* __restrict__ totals,
                                                  int* __restrict__ bstart,
                                                  uintT* __restrict__ tmp, int nbuck,
                                                  const float* __restrict__ A,
                                                  const ushortT* __restrict__ Bt,
                                                  ucharT* __restrict__ h1i,
                                                  float* __restrict__ hsc,
                                                  float* __restrict__ s1s,
                                                  float* __restrict__ s1d,
                                                  int M, int nPrim, int slabBase) {
    if (blockIdx.x >= nPrim) {
        int wave = threadIdx.x >> 6;
        int slab = slabBase + (blockIdx.x - nPrim) * 4 + wave;
        dev_gemm1(slab, A, Bt, h1i, hsc, s1s, s1d, M);
        return;
    }
    __shared__ int st[1024];
    __shared__ int pos[1024];
    __shared__ int wsum[4];
    int t = threadIdx.x, lane = t & 63, wv = t >> 6;
    int b = blockIdx.x;
    // exclusive scan of totals -> bucket starts (st)
    int g[4];
    int s = 0;
    #pragma unroll
    for (int j = 0; j < 4; ++j) {
        int e = 4 * t + j;
        g[j] = (e < nbuck) ? totals[e] : 0;
        s += g[j];
    }
    int incl = s;
    #pragma unroll
    for (int off = 1; off < 64; off <<= 1) {
        int u = __shfl_up(incl, off, 64);
        if (lane >= off) incl += u;
    }
    if (lane == 63) wsum[wv] = incl;
    __syncthreads();
    int add = 0;
    if (wv > 0) add += wsum[0];
    if (wv > 1) add += wsum[1];
    if (wv > 2) add += wsum[2];
    int excl = incl + add - s;
    #pragma unroll
    for (int j = 0; j < 4; ++j) {
        int e = 4 * t + j;
        if (e < nbuck) st[e] = excl;
        excl += g[j];
    }
    __syncthreads();
    const int* crow = counts + (size_t)b * nbuck;
    for (int i = t; i < nbuck; i += 256) {
        int sv = st[i];
        pos[i] = sv + crow[i];
        if (b == 0) bstart[i] = sv;
    }
    __syncthreads();
    int base = b * EPB;
    #pragma unroll
    for (int r = 0; r < 4; ++r) {
        int i4 = base + (r * 256 + t) * 4;
        if (i4 + 3 < E) {
            int4 sv = *(const int4*)(ei + i4);
            int4 dv = *(const int4*)(ei + E + i4);
            int p0 = atomicAdd(&pos[dv.x >> 7], 1);
            tmp[p0] = (uintT)sv.x | (((uintT)dv.x & 127u) << 17);
            int p1 = atomicAdd(&pos[dv.y >> 7], 1);
            tmp[p1] = (uintT)sv.y | (((uintT)dv.y & 127u) << 17);
            int p2 = atomicAdd(&pos[dv.z >> 7], 1);
            tmp[p2] = (uintT)sv.z | (((uintT)dv.z & 127u) << 17);
            int p3 = atomicAdd(&pos[dv.w >> 7], 1);
            tmp[p3] = (uintT)sv.w | (((uintT)dv.w & 127u) << 17);
        } else {
            for (int j = i4; j < E; ++j) {
                int sj = ei[j], dj = ei[E + j];
                int p = atomicAdd(&pos[dj >> 7], 1);
                tmp[p] = (uintT)sj | (((uintT)dj & 127u) << 17);
            }
        }
    }
}

// ---------------- P4: per-bucket CSR finalize (+ gemm chunk) ---------------
__global__ __launch_bounds__(256) void k_csr_g1(const uintT* __restrict__ tmp,
                                                const int* __restrict__ bstart,
                                                const int* __restrict__ totals,
                                                int* __restrict__ rowptr,
                                                int* __restrict__ csr_src,
                                                int N, int nbuck,
                                                const float* __restrict__ A,
                                                const ushortT* __restrict__ Bt,
                                                ucharT* __restrict__ h1i,
                                                float* __restrict__ hsc,
                                                float* __restrict__ s1s,
                                                float* __restrict__ s1d,
                                                int M, int nPrim, int slabBase) {
    if (blockIdx.x >= nPrim) {
        int wave = threadIdx.x >> 6;
        int slab = slabBase + (blockIdx.x - nPrim) * 4 + wave;
        dev_gemm1(slab, A, Bt, h1i, hsc, s1s, s1d, M);
        return;
    }
    __shared__ int cnt[128];
    __shared__ int cur[128];
    __shared__ int wtot;
    int k = blockIdx.x;
    int t = threadIdx.x;
    int nodeBase = k << 7;
    int nn = N - nodeBase;
    if (nn > 128) nn = 128;
    int myStart = bstart[k];
    int myCount = totals[k];
    int csrBase = myStart + nodeBase;   // + self loops of preceding nodes
    if (t < 128) cnt[t] = 0;
    __syncthreads();
    for (int i = t; i < myCount; i += 256) {
        uintT p = tmp[myStart + i];
        atomicAdd(&cnt[p >> 17], 1);
    }
    __syncthreads();
    int dseg = 0, incl = 0;
    if (t < 128) {
        dseg = (t < nn) ? cnt[t] + 1 : 0;   // +1 self loop
        incl = dseg;
        #pragma unroll
        for (int off = 1; off < 64; off <<= 1) {
            int u = __shfl_up(incl, off, 64);
            if ((t & 63) >= off) incl += u;
        }
        if (t == 63) wtot = incl;
    }
    __syncthreads();
    if (t < nn) {
        int excl = incl - dseg + ((t >= 64) ? wtot : 0);
        int rp = csrBase + excl;
        int node = nodeBase + t;
        rowptr[node + 1] = rp + dseg;
        csr_src[rp] = node;              // self loop first
        cur[t] = rp + 1;
    }
    if (k == 0 && t == 0) rowptr[0] = 0;
    __syncthreads();
    for (int i = t; i < myCount; i += 256) {
        uintT p = tmp[myStart + i];
        int ld = p >> 17;
        int q = atomicAdd(&cur[ld], 1);
        csr_src[q] = (int)(p & 0x1FFFFu);
    }
}

// ---------------- layer-1 aggregation --------------------------------------
// 16 ch/lane (uint4), 16 lanes/edge, 4 edges/wave; rotation-free 3x unroll.
struct Edge1 {
    float sv, sc;
    uint4 v;
};

static __device__ __forceinline__ void ld1(Edge1& S, int j, int end,
                                           const int* __restrict__ csr_src,
                                           const float* __restrict__ ssrc,
                                           const float* __restrict__ hsc,
                                           const ucharT* __restrict__ hb, int head) {
    if (j < end) {
        int s = csr_src[j];
        S.sv = ssrc[(size_t)s * 8 + head];
        S.sc = hsc[s];
        S.v = *(const uint4*)(hb + (size_t)s * 256);
    }
}

static __device__ __forceinline__ void ac1(const Edge1& S, float sdn,
                                           float2v* A, float& l, float& sps) {
    float p = __expf(lrelu(S.sv + sdn));
    l += p;
    float ps = p * S.sc;
    sps += ps;
    float2v p2 = {ps, ps};
    uintT w;
    w = S.v.x;
    A[0] += p2 * (float2v){ub(w, 0), ub(w, 1)};
    A[1] += p2 * (float2v){ub(w, 2), ub(w, 3)};
    w = S.v.y;
    A[2] += p2 * (float2v){ub(w, 0), ub(w, 1)};
    A[3] += p2 * (float2v){ub(w, 2), ub(w, 3)};
    w = S.v.z;
    A[4] += p2 * (float2v){ub(w, 0), ub(w, 1)};
    A[5] += p2 * (float2v){ub(w, 2), ub(w, 3)};
    w = S.v.w;
    A[6] += p2 * (float2v){ub(w, 0), ub(w, 1)};
    A[7] += p2 * (float2v){ub(w, 2), ub(w, 3)};
}

__global__ __launch_bounds__(256) void k_agg1(const ucharT* __restrict__ h1i,
                                              const float* __restrict__ hsc,
                                              const float* __restrict__ ssrc,
                                              const float* __restrict__ sdst,
                                              const int* __restrict__ rowptr,
                                              const int* __restrict__ csr_src,
                                              const float* __restrict__ b1,
                                              ushortT* __restrict__ out1, int N) {
    int lane = threadIdx.x & 63;
    int wid = threadIdx.x >> 6;
    int n = blockIdx.x * 4 + wid;
    if (n >= N) return;
    int g = lane >> 4;           // 4 edge slots
    int cl = lane & 15;          // 16 channels each
    int head = cl >> 1;
    int beg = rowptr[n], end = rowptr[n + 1];
    float sdn = sdst[(size_t)n * 8 + head];
    const ucharT* hb = h1i + cl * 16;
    float2v A[8];
    #pragma unroll
    for (int k = 0; k < 8; ++k) A[k] = (float2v){0.f, 0.f};
    float l = 0.f, sps = 0.f;
    int i0 = beg + g;
    if (i0 < end) {
        Edge1 S0, S1, S2;
        S0.sv = S1.sv = S2.sv = 0.f;
        S0.sc = S1.sc = S2.sc = 0.f;
        S0.v = S1.v = S2.v = make_uint4(0u, 0u, 0u, 0u);
        ld1(S0, i0, end, csr_src, ssrc, hsc, hb, head);
        ld1(S1, i0 + 4, end, csr_src, ssrc, hsc, hb, head);
        ld1(S2, i0 + 8, end, csr_src, ssrc, hsc, hb, head);
        for (int idx = i0; idx < end; idx += 12) {
            ac1(S0, sdn, A, l, sps);
            ld1(S0, idx + 12, end, csr_src, ssrc, hsc, hb, head);
            if (idx + 4 < end) {
                ac1(S1, sdn, A, l, sps);
                ld1(S1, idx + 16, end, csr_src, ssrc, hsc, hb, head);
            }
            if (idx + 8 < end) {
                ac1(S2, sdn, A, l, sps);
                ld1(S2, idx + 20, end, csr_src, ssrc, hsc, hb, head);
            }
        }
    }
    // reduce across the 4 edge-slot groups (lanes differing in bits 4,5)
    #pragma unroll
    for (int off = 16; off < 64; off <<= 1) {
        l += __shfl_xor(l, off, 64);
        sps += __shfl_xor(sps, off, 64);
        #pragma unroll
        for (int k = 0; k < 8; ++k) {
            A[k].x += __shfl_xor(A[k].x, off, 64);
            A[k].y += __shfl_xor(A[k].y, off, 64);
        }
    }
    if (g == 0) {
        float inv = 1.f / l;
        float adj = 128.f * sps;            // undo the uint8 bias
        const float4 bb0 = *(const float4*)(b1 + cl * 16);
        const float4 bb1 = *(const float4*)(b1 + cl * 16 + 4);
        const float4 bb2 = *(const float4*)(b1 + cl * 16 + 8);
        const float4 bb3 = *(const float4*)(b1 + cl * 16 + 12);
        float bbf[16] = {bb0.x, bb0.y, bb0.z, bb0.w, bb1.x, bb1.y, bb1.z, bb1.w,
                         bb2.x, bb2.y, bb2.z, bb2.w, bb3.x, bb3.y, bb3.z, bb3.w};
        uintT o[8];
        #pragma unroll
        for (int k = 0; k < 8; ++k) {
            float x0 = fmaxf((A[k].x - adj) * inv + bbf[2 * k], 0.f);
            float x1 = fmaxf((A[k].y - adj) * inv + bbf[2 * k + 1], 0.f);
            o[k] = pk(x0, x1);
        }
        *(uint4*)(out1 + (size_t)n * 256 + cl * 16) =
            make_uint4(o[0], o[1], o[2], o[3]);
        *(uint4*)(out1 + (size_t)n * 256 + cl * 16 + 8) =
            make_uint4(o[4], o[5], o[6], o[7]);
    }
}

// ---------------- GEMM2: out1b[M,256] @ W2 -> bf16 h2b[M,40] + scores2 -----
__global__ __launch_bounds__(256) void k_gemm2(const ushortT* __restrict__ X,
                                               const ushortT* __restrict__ Bt,
                                               const float* __restrict__ a2s,
                                               const float* __restrict__ a2d,
                                               ushortT* __restrict__ H2,
                                               float* __restrict__ s2s,
                                               float* __restrict__ s2d, int M) {
    int lane = threadIdx.x & 63, wave = threadIdx.x >> 6;
    int slab = blockIdx.x * 4 + wave;
    int r0 = slab * 16;
    if (r0 >= M) return;
    int n = lane & 15, q = lane >> 4;
    const ushortT* xrow = X + (size_t)(r0 + n) * 256 + q * 8;
    float4v acc[3];
    #pragma unroll
    for (int j = 0; j < 3; ++j) acc[j] = (float4v){0.f, 0.f, 0.f, 0.f};
    #pragma unroll
    for (int s = 0; s < 8; ++s) {
        short8 a = *(const short8*)(xrow + s * 32);
        #pragma unroll
        for (int j = 0; j < 3; ++j) {
            short8 b = *(const short8*)(Bt + (size_t)(j * 16 + n) * 256 + s * 32 + q * 8);
            acc[j] = __builtin_amdgcn_mfma_f32_16x16x32_bf16(a, b, acc[j], 0, 0, 0);
        }
    }
    float asv[3], adv[3];
    #pragma unroll
    for (int j = 0; j < 3; ++j) {
        int col = j * 16 + n;
        asv[j] = (col < 40) ? a2s[col] : 0.f;
        adv[j] = (col < 40) ? a2d[col] : 0.f;
    }
    float us[4], ud[4];
    #pragma unroll
    for (int r = 0; r < 4; ++r) {
        us[r] = acc[0][r] * asv[0] + acc[1][r] * asv[1] + acc[2][r] * asv[2];
        ud[r] = acc[0][r] * adv[0] + acc[1][r] * adv[1] + acc[2][r] * adv[2];
    }
    #pragma unroll
    for (int off = 1; off < 16; off <<= 1) {
        #pragma unroll
        for (int r = 0; r < 4; ++r) {
            us[r] += __shfl_xor(us[r], off, 64);
            ud[r] += __shfl_xor(ud[r], off, 64);
        }
    }
    #pragma unroll
    for (int j = 0; j < 3; ++j) {
        int col = j * 16 + n;
        if (col < 40) {
            #pragma unroll
            for (int r = 0; r < 4; ++r)
                H2[(size_t)(r0 + q * 4 + r) * 40 + col] = f2bf(acc[j][r]);
        }
    }
    if (n == 0) {
        #pragma unroll
        for (int r = 0; r < 4; ++r) {
            int row = r0 + q * 4 + r;
            s2s[row] = us[r];
            s2d[row] = ud[r];
        }
    }
}

// ---------------- layer-2 aggregation + log_softmax ------------------------
struct Edge2 {
    float sv;
    uint2 v;
};

static __device__ __forceinline__ void ld2(Edge2& S, int j, int end,
                                           const int* __restrict__ csr_src,
                                           const float* __restrict__ ss,
                                           const ushortT* __restrict__ h2, int cl) {
    if (j < end) {
        int s = csr_src[j];
        S.sv = ss[s];
        S.v = *(const uint2*)(h2 + (size_t)s * 40 + cl * 4);
    }
}

static __device__ __forceinline__ void ac2(const Edge2& S, float sdn,
                                           float2v& A01, float2v& A23, float& l) {
    float p = __expf(lrelu(S.sv + sdn));
    l += p;
    float2v p2 = {p, p};
    A01 += p2 * (float2v){bflo(S.v.x), bfhi(S.v.x)};
    A23 += p2 * (float2v){bflo(S.v.y), bfhi(S.v.y)};
}

__global__ __launch_bounds__(256) void k_agg2lsm(const ushortT* __restrict__ h2,
                                                 const float* __restrict__ ss,
                                                 const float* __restrict__ sd,
                                                 const int* __restrict__ rowptr,
                                                 const int* __restrict__ csr_src,
                                                 const float* __restrict__ b2,
                                                 float* __restrict__ out, int N) {
    int lane = threadIdx.x & 63;
    int wid = threadIdx.x >> 6;
    int n = blockIdx.x * 4 + wid;
    if (n >= N) return;
    int el = lane / 10;
    int cl = lane - el * 10;
    int beg = rowptr[n], end = rowptr[n + 1];
    float sdn = sd[n];
    float2v A01 = (float2v){0.f, 0.f}, A23 = (float2v){0.f, 0.f};
    float l = 0.f;
    if (el < 6) {
        int i0 = beg + el;
        if (i0 < end) {
            Edge2 S0, S1, S2;
            S0.sv = S1.sv = S2.sv = 0.f;
            S0.v = S1.v = S2.v = make_uint2(0u, 0u);
            ld2(S0, i0, end, csr_src, ss, h2, cl);
            ld2(S1, i0 + 6, end, csr_src, ss, h2, cl);
            ld2(S2, i0 + 12, end, csr_src, ss, h2, cl);
            for (int idx = i0; idx < end; idx += 18) {
                ac2(S0, sdn, A01, A23, l);
                ld2(S0, idx + 18, end, csr_src, ss, h2, cl);
                if (idx + 6 < end) {
                    ac2(S1, sdn, A01, A23, l);
                    ld2(S1, idx + 24, end, csr_src, ss, h2, cl);
                }
                if (idx + 12 < end) {
                    ac2(S2, sdn, A01, A23, l);
                    ld2(S2, idx + 30, end, csr_src, ss, h2, cl);
                }
            }
        }
    }
    float a0 = A01.x, a1 = A01.y, a2 = A23.x, a3 = A23.y;
    // reduce the 6 slots into lanes 0..9
    float t0 = 0.f, t1 = 0.f, t2 = 0.f, t3 = 0.f, lt = 0.f;
    #pragma unroll
    for (int k = 0; k < 6; ++k) {
        int sl = cl + 10 * k;
        t0 += __shfl(a0, sl, 64);
        t1 += __shfl(a1, sl, 64);
        t2 += __shfl(a2, sl, 64);
        t3 += __shfl(a3, sl, 64);
        if (cl == 0) lt += __shfl(l, sl, 64);
    }
    lt = __shfl(lt, 0, 64);
    float inv = 1.f / lt;
    float o0 = t0 * inv + b2[cl * 4 + 0];
    float o1 = t1 * inv + b2[cl * 4 + 1];
    float o2 = t2 * inv + b2[cl * 4 + 2];
    float o3 = t3 * inv + b2[cl * 4 + 3];
    float lm = (lane < 10) ? fmaxf(fmaxf(o0, o1), fmaxf(o2, o3)) : -INFINITY;
    #pragma unroll
    for (int off = 32; off; off >>= 1) lm = fmaxf(lm, __shfl_xor(lm, off, 64));
    float le = (lane < 10)
        ? __expf(o0 - lm) + __expf(o1 - lm) + __expf(o2 - lm) + __expf(o3 - lm)
        : 0.f;
    #pragma unroll
    for (int off = 32; off; off >>= 1) le += __shfl_xor(le, off, 64);
    float ls = lm + logf(le);
    if (lane < 10) {
        float4 w = make_float4(o0 - ls, o1 - ls, o2 - ls, o3 - ls);
        *(float4*)(out + (size_t)n * 40 + cl * 4) = w;
    }
}

// ---------------------------------------------------------------------------
extern "C" void kernel_launch(void* const* d_in, const int* in_sizes, int n_in,
                              void* d_out, int out_size, void* d_ws, size_t ws_size,
                              hipStream_t stream) {
    const float* x   = (const float*)d_in[0];
    const int*   ei  = (const int*)d_in[1];
    const float* W1  = (const float*)d_in[2];
    const float* a1s = (const float*)d_in[3];
    const float* a1d = (const float*)d_in[4];
    const float* b1  = (const float*)d_in[5];
    const float* W2  = (const float*)d_in[6];
    const float* a2s = (const float*)d_in[7];
    const float* a2d = (const float*)d_in[8];
    const float* b2  = (const float*)d_in[9];
    float* out = (float*)d_out;

    const int N = in_sizes[0] / 128;   // 100000
    const int E = in_sizes[1] / 2;     // 1600000
    const int ET = E + N;
    const int NBUCK = (N + 127) >> 7;              // 782
    const int NB1 = (E + EPB - 1) / EPB;           // 391

    // ---- workspace layout ----
    char* w = (char*)d_ws;
    ucharT* h1i = (ucharT*)w;                             // N*256 u8 (25.6 MB)
    float* hsc  = (float*)(w + (size_t)N * 256);          // N f32 row scales
    ushortT* out1b = (ushortT*)(w + (size_t)N * 256 + (size_t)N * 4);  // N*256 bf16
    float* s1s  = (float*)(out1b + (size_t)N * 256);      // N*8
    float* s1d  = s1s + (size_t)N * 8;
    int* i_cnt = (int*)(s1d + (size_t)N * 8);             // NB1*NBUCK
    int* i_tot = i_cnt + (size_t)NB1 * NBUCK;             // NBUCK
    int* i_bst = i_tot + NBUCK + 2;                       // NBUCK
    int* i_row = i_bst + NBUCK + 2;                       // N+1
    uintT* i_tmp = (uintT*)(i_row + N + 16);              // E packed pairs
    int* i_csr = (int*)(i_tmp + E);                       // ET ints
    ushortT* W1t = (ushortT*)(i_csr + ET);                // 272*128 bf16
    ushortT* W2t = W1t + 272 * 128;                       // 48*256 bf16
    // layer-2 overlays h1i (dead after k_agg1)
    ushortT* h2b = (ushortT*)w;                           // N*40 bf16 (8 MB)
    float* s2s = (float*)(w + (size_t)N * 40 * 2);        // N
    float* s2d = s2s + N;                                 // N

    const int nb4 = (N + 3) / 4;
    const int nbG = (N / 16 + 3) / 4;            // gemm1 blocks (4 waves x 16 rows)
    const int CH  = (nbG + 2) / 3;               // gemm1 chunk (blocks)

    // ---- L0: weight prep ----
    k_prep<<<PREP_BLOCKS, 256, 0, stream>>>(W1, W2, a1s, a1d, W1t, W2t);
    // ---- P1: bucket histogram ∥ gemm1 chunk 0 ----
    k_cnt_g1<<<NB1 + CH, 256, 0, stream>>>(ei, E, i_cnt, NBUCK,
                                           x, W1t, h1i, hsc, s1s, s1d,
                                           N, NB1, 0);
    // ---- P2: per-bucket scan across blocks ----
    k_scan_cols<<<NBUCK, 256, 0, stream>>>(i_cnt, i_tot, NB1, NBUCK);
    // ---- P3: bucket-contiguous placement ∥ gemm1 chunk 1 ----
    k_place_g1<<<NB1 + CH, 256, 0, stream>>>(ei, E, i_cnt, i_tot, i_bst, i_tmp, NBUCK,
                                             x, W1t, h1i, hsc, s1s, s1d,
                                             N, NB1, CH * 4);
    // ---- P4: per-bucket CSR finalize ∥ gemm1 chunk 2 ----
    k_csr_g1<<<NBUCK + CH, 256, 0, stream>>>(i_tmp, i_bst, i_tot, i_row, i_csr,
                                             N, NBUCK,
                                             x, W1t, h1i, hsc, s1s, s1d,
                                             N, NBUCK, CH * 8);

    // ---- layer 1 aggregation ----
    k_agg1<<<nb4, 256, 0, stream>>>(h1i, hsc, s1s, s1d, i_row, i_csr, b1, out1b, N);

    // ---- layer 2 ----
    k_gemm2<<<nbG, 256, 0, stream>>>(out1b, W2t, a2s, a2d, h2b, s2s, s2d, N);
    k_agg2lsm<<<nb4, 256, 0, stream>>>(h2b, s2s, s2d, i_row, i_csr, b2, out, N);
}